// Round 14
// baseline (629.793 us; speedup 1.0000x reference)
//
#include <hip/hip_runtime.h>
#include <stdint.h>

#define S_LEN 2048
#define B_SZ 4
#define DM 512
#define NTOK (B_SZ * S_LEN)

typedef unsigned short u16;
typedef unsigned int u32;
typedef unsigned long long u64;
typedef __attribute__((ext_vector_type(8))) short short8;
typedef __attribute__((ext_vector_type(4))) float f32x4;

typedef const __attribute__((address_space(1))) u32 gq_t;
typedef __attribute__((address_space(3))) u32 lq_t;

__device__ __forceinline__ u16 f2bf(float f) {
  union { float f; u32 u; } v; v.f = f;
  return (u16)((v.u + 0x7FFFu + ((v.u >> 16) & 1u)) >> 16);
}

__device__ __forceinline__ float bf2f(u32 hi16_at_lo) {
  union { u32 u; float f; } v; v.u = hi16_at_lo;
  return v.f;
}

__device__ __forceinline__ float fexp2(float x) {
#if __has_builtin(__builtin_amdgcn_exp2f)
  return __builtin_amdgcn_exp2f(x);
#else
  return exp2f(x);
#endif
}

__device__ __forceinline__ short8 mk8(u64 a, u64 b) {
  union { u64 q[2]; short8 s; } u;
  u.q[0] = a; u.q[1] = b;
  return u.s;
}

// swap X.hi32lanes <-> Y.lo32lanes
__device__ __forceinline__ void swap32(u32& x, u32& y) {
  asm("v_permlane32_swap_b32 %0, %1" : "+v"(x), "+v"(y));
}
// swap lanes16-31 of X with lanes0-15 of Y (per 32-lane block)
__device__ __forceinline__ void swap16(u32& x, u32& y, int lane) {
#if __has_builtin(__builtin_amdgcn_permlane16_swap)
  asm("v_permlane16_swap_b32 %0, %1" : "+v"(x), "+v"(y));
#else
  u32 tx = __builtin_amdgcn_ds_swizzle(x, 0x401F);   // lane^16
  u32 ty = __builtin_amdgcn_ds_swizzle(y, 0x401F);
  bool up = (lane & 16) != 0;
  u32 nx = up ? ty : x;
  u32 ny = up ? y : tx;
  x = nx; y = ny;
#endif
}

// ---------------- embed: x = bf16(tok_embed[ids] + pe) ----------------
__global__ void embed_kernel(const int* __restrict__ ids, const float* __restrict__ te,
                             const float* __restrict__ pe, u16* __restrict__ xb) {
  int gid = blockIdx.x * 256 + threadIdx.x;   // NTOK*128 threads total
  int tok = gid >> 7, c4 = (gid & 127) << 2;
  int s = tok & (S_LEN - 1);
  int id = ids[tok];
  const float4 a = *(const float4*)(te + (long)id * DM + c4);
  const float4 p = *(const float4*)(pe + (long)s * DM + c4);
  uint2 pk;
  pk.x = (u32)f2bf(a.x + p.x) | ((u32)f2bf(a.y + p.y) << 16);
  pk.y = (u32)f2bf(a.z + p.z) | ((u32)f2bf(a.w + p.w) << 16);
  *(uint2*)(xb + (long)tok * DM + c4) = pk;
}

// ------------- weight prep via LDS 64x64 tile transpose (coalesced both sides) -------------
__global__ void wconv_all(const float* __restrict__ Wq, const float* __restrict__ Wk,
                          const float* __restrict__ Wv, const float* __restrict__ Wo,
                          const float* __restrict__ W1, const float* __restrict__ W2,
                          u16* __restrict__ WqkvT, u16* __restrict__ WoT,
                          u16* __restrict__ W1T, u16* __restrict__ W2T) {
  __shared__ u16 t_lds[64 * 65];
  const int tile = blockIdx.x;
  const float* src; u16* dst; int N, K, kt, nt, l;
  if (tile < 768) {                            // Wq|Wk|Wv -> WqkvT panels
    int which = tile >> 8, r = tile & 255;
    l = r >> 6; int rr = r & 63; kt = rr >> 3; nt = rr & 7;
    src = (which == 0 ? Wq : which == 1 ? Wk : Wv) + (long)l * 512 * 512;
    N = 512; K = 512;
    dst = WqkvT + (long)l * 1536 * 512 + (long)(which * 512) * 512;
  } else if (tile < 1024) {                    // Wo
    int r = tile - 768;
    l = r >> 6; int rr = r & 63; kt = rr >> 3; nt = rr & 7;
    src = Wo + (long)l * 512 * 512; N = 512; K = 512;
    dst = WoT + (long)l * 512 * 512;
  } else if (tile < 2048) {                    // W1: K=512, N=2048
    int r = tile - 1024;
    l = r >> 8; int rr = r & 255; kt = rr >> 5; nt = rr & 31;
    src = W1 + (long)l * 512 * 2048; N = 2048; K = 512;
    dst = W1T + (long)l * 2048 * 512;
  } else {                                     // W2: K=2048, N=512
    int r = tile - 2048;
    l = r >> 8; int rr = r & 255; kt = rr >> 3; nt = rr & 7;
    src = W2 + (long)l * 2048 * 512; N = 512; K = 2048;
    dst = W2T + (long)l * 512 * 2048;
  }
  const int tr = threadIdx.x >> 4;
  const int tc = (threadIdx.x & 15) << 2;
#pragma unroll
  for (int i = 0; i < 4; ++i) {
    int k = tr + i * 16;
    const float4 v = *(const float4*)(src + (long)(kt * 64 + k) * N + nt * 64 + tc);
    t_lds[(tc + 0) * 65 + k] = f2bf(v.x);
    t_lds[(tc + 1) * 65 + k] = f2bf(v.y);
    t_lds[(tc + 2) * 65 + k] = f2bf(v.z);
    t_lds[(tc + 3) * 65 + k] = f2bf(v.w);
  }
  __syncthreads();
#pragma unroll
  for (int i = 0; i < 4; ++i) {
    int n = tr + i * 16;
    u16 a0 = t_lds[n * 65 + tc + 0];
    u16 a1 = t_lds[n * 65 + tc + 1];
    u16 a2 = t_lds[n * 65 + tc + 2];
    u16 a3 = t_lds[n * 65 + tc + 3];
    uint2 pk;
    pk.x = (u32)a0 | ((u32)a1 << 16);
    pk.y = (u32)a2 | ((u32)a3 << 16);
    *(uint2*)(dst + (long)(nt * 64 + n) * K + kt * 64 + tc) = pk;
  }
}

// ---------------- GEMM (unchanged from round 13) ----------------
template <int BM, int BN, bool RELU, bool VSPLIT, bool SWAPC>
__global__ __launch_bounds__(BM * 2) void gemm_kernel(const u16* __restrict__ A,
                                                      const u16* __restrict__ BT,
                                                      void* __restrict__ Cout,
                                                      u16* __restrict__ vt,
                                                      int M, int N, int K) {
  constexpr int NI = BN / 32;
  constexpr int NW = BM / 32;
  constexpr int BRW = BN / NW;
  constexpr int LOADS = 4 + BRW / 8;
  __shared__ __align__(16) u16 a_t[2][BM * 64];
  __shared__ __align__(16) u16 b_t[2][BN * 64];
  const int tid = threadIdx.x;
  const int w = tid >> 6, lane = tid & 63;
  const int wr = w >> 1, wc = w & 1;
  const int g = lane >> 4, lr = lane & 15;
  const int l8 = lane >> 3, lch = lane & 7;
  const int gc = lch ^ l8;
  const int nwg = gridDim.x * gridDim.y;
  const int bid = blockIdx.x + gridDim.x * blockIdx.y;
  const int cpx = nwg >> 3;
  const int swz = (bid & 7) * cpx + (bid >> 3);
  const int bx = swz % gridDim.x, by = swz / gridDim.x;
  const long m0 = (long)by * BM, n0 = (long)bx * BN;
  f32x4 acc[4][NI] = {};
  const int nk = K >> 6;

  auto stage = [&](int nb, int kt) {
    const int k0 = kt << 6;
#pragma unroll
    for (int i = 0; i < 4; ++i) {
      int row = w * 32 + i * 8 + l8;
      __builtin_amdgcn_global_load_lds((gq_t*)(A + (m0 + row) * K + k0 + gc * 8),
                                       (lq_t*)&a_t[nb][(w * 4 + i) * 512], 16, 0, 0);
    }
#pragma unroll
    for (int i = 0; i < BRW / 8; ++i) {
      int row = w * BRW + i * 8 + l8;
      __builtin_amdgcn_global_load_lds((gq_t*)(BT + (n0 + row) * K + k0 + gc * 8),
                                       (lq_t*)&b_t[nb][(w * (BRW / 8) + i) * 512], 16, 0, 0);
    }
  };

  stage(0, 0);
  stage(1, 1);
  for (int kt = 0; kt < nk; ++kt) {
    const int cur = kt & 1;
    if (kt + 1 < nk) {
      if constexpr (LOADS == 6) asm volatile("s_waitcnt vmcnt(6)" ::: "memory");
      else                      asm volatile("s_waitcnt vmcnt(5)" ::: "memory");
    } else {
      asm volatile("s_waitcnt vmcnt(0)" ::: "memory");
    }
    __builtin_amdgcn_s_barrier();
    __builtin_amdgcn_sched_barrier(0);
    short8 af[2][4], bfr[2][NI];
#pragma unroll
    for (int ks = 0; ks < 2; ++ks) {
#pragma unroll
      for (int mi = 0; mi < 4; ++mi) {
        int row = wr * 64 + mi * 16 + lr;
        int byte = row * 128 + (((ks * 4 + g) ^ (row & 7)) << 4);
        af[ks][mi] = *(const short8*)((const char*)a_t[cur] + byte);
      }
#pragma unroll
      for (int ni = 0; ni < NI; ++ni) {
        int row = wc * (BN / 2) + ni * 16 + lr;
        int byte = row * 128 + (((ks * 4 + g) ^ (row & 7)) << 4);
        bfr[ks][ni] = *(const short8*)((const char*)b_t[cur] + byte);
      }
    }
    asm volatile("s_waitcnt lgkmcnt(0)" ::: "memory");
    __builtin_amdgcn_s_barrier();
    __builtin_amdgcn_sched_barrier(0);
    if (kt + 2 < nk) stage(cur, kt + 2);
#pragma unroll
    for (int ks = 0; ks < 2; ++ks)
#pragma unroll
      for (int mi = 0; mi < 4; ++mi)
#pragma unroll
        for (int ni = 0; ni < NI; ++ni) {
          if constexpr (SWAPC)
            acc[mi][ni] = __builtin_amdgcn_mfma_f32_16x16x32_bf16(bfr[ks][ni], af[ks][mi], acc[mi][ni], 0, 0, 0);
          else
            acc[mi][ni] = __builtin_amdgcn_mfma_f32_16x16x32_bf16(af[ks][mi], bfr[ks][ni], acc[mi][ni], 0, 0, 0);
        }
  }

  if constexpr (VSPLIT) {
    if (n0 >= 1024) {
#pragma unroll
      for (int mi = 0; mi < 4; ++mi)
#pragma unroll
        for (int ni = 0; ni < NI; ++ni) {
          int vc = (int)(n0 - 1024) + wc * (BN / 2) + ni * 16 + lr;   // h*64 + d
          int hh = vc >> 6, d = vc & 63;
          long tok0 = m0 + wr * 64 + mi * 16 + g * 4;
          int bb = (int)(tok0 >> 11), s0 = (int)(tok0 & 2047);
          uint2 pk;
          pk.x = (u32)f2bf(acc[mi][ni][0]) | ((u32)f2bf(acc[mi][ni][1]) << 16);
          pk.y = (u32)f2bf(acc[mi][ni][2]) | ((u32)f2bf(acc[mi][ni][3]) << 16);
          *(uint2*)(vt + (((long)bb * 8 + hh) * 64 + d) * 2048 + s0) = pk;
        }
      return;
    }
  }
  if constexpr (SWAPC) {
#pragma unroll
    for (int mi = 0; mi < 4; ++mi)
#pragma unroll
      for (int ni = 0; ni < NI; ++ni) {
        long grow = m0 + wr * 64 + mi * 16 + lr;
        long gcb = n0 + wc * (BN / 2) + ni * 16 + 4 * g;
        float v0 = acc[mi][ni][0], v1 = acc[mi][ni][1], v2 = acc[mi][ni][2], v3 = acc[mi][ni][3];
        if (RELU) {
          v0 = fmaxf(v0, 0.f); v1 = fmaxf(v1, 0.f); v2 = fmaxf(v2, 0.f); v3 = fmaxf(v3, 0.f);
        }
        uint2 pk;
        pk.x = (u32)f2bf(v0) | ((u32)f2bf(v1) << 16);
        pk.y = (u32)f2bf(v2) | ((u32)f2bf(v3) << 16);
        *(uint2*)((u16*)Cout + grow * N + gcb) = pk;
      }
  } else {
#pragma unroll
    for (int mi = 0; mi < 4; ++mi)
#pragma unroll
      for (int ni = 0; ni < NI; ++ni)
#pragma unroll
        for (int j = 0; j < 4; ++j) {
          long grow = m0 + wr * 64 + mi * 16 + g * 4 + j;
          long gcol = n0 + wc * (BN / 2) + ni * 16 + lr;
          float v = acc[mi][ni][j];
          if (RELU) v = fmaxf(v, 0.f);
          ((u16*)Cout)[grow * N + gcol] = f2bf(v);
        }
  }
}

// ---------------- flash attention, KV-split x2 ----------------
// block = (b, h, q-tile, KV-half): 8 waves x 16 q; processes 1024 keys; writes UNNORMALIZED
// partial O (bf16) + partial l (max-free softmax sums merge exactly). LDS trimmed to ~35KB:
// q_t aliases k_t (dead after prologue); single shared ones-block for the l-row.
// grid 1024 = 4 blocks/CU = 32 waves/CU (100% occupancy cap).
__global__ __launch_bounds__(512) void attn_kernel(const u16* __restrict__ qkv,
                                                   const u16* __restrict__ vt,
                                                   const int* __restrict__ mask,
                                                   u16* __restrict__ o0dst,
                                                   u16* __restrict__ o1dst,
                                                   float* __restrict__ lbuf) {
  __shared__ __align__(16) u16 kv[2 * 4096 + 2 * 4096 + 1024];  // k_t[2] | v_t[2] | vone
  __shared__ __align__(16) float mvals[2][64];
  const int tid = threadIdx.x;
  const int w = tid >> 6, lane = tid & 63;
  const int g = lane >> 4, lr = lane & 15;
  const int l8 = lane >> 3, lch = lane & 7;
  const int gc = lch ^ l8;
  const int half = blockIdx.x & 1, q0 = (blockIdx.x >> 1) * 128;
  const int b = blockIdx.z, h = blockIdx.y;
  const int kb0 = half * 1024;
  const long base = (long)b * S_LEN * 1536;
  const int qcol = h * 64, kcol = 512 + h * 64;
  const u16* vhead = vt + (((long)b * 8 + h) * 64) * 2048;
  u16* q_t = kv;                                 // aliases k_t[0..1]; prologue only
  u16* vone = kv + 16384;
  const float SC = 0.18033688011112042f;         // 0.125 * log2(e)

  auto stageKV = [&](int nb, int kb) {
    int row = w * 8 + l8;
    __builtin_amdgcn_global_load_lds((gq_t*)(qkv + base + (long)(kb + row) * 1536 + kcol + gc * 8),
                                     (lq_t*)(kv + nb * 4096 + w * 512), 16, 0, 0);
    __builtin_amdgcn_global_load_lds((gq_t*)(vhead + (long)row * 2048 + kb + gc * 8),
                                     (lq_t*)(kv + 8192 + nb * 4096 + w * 512), 16, 0, 0);
    if (tid < 64) mvals[nb][tid] = (mask[b * S_LEN + kb + tid] == 0) ? -1e9f : 0.f;
  };

  // ---- prologue: vone init + Q stage (into aliased region) -> qf -> KV tile 0 ----
  {
    u32 val = ((tid >> 5) == 0) ? 0x3F803F80u : 0u;   // row 0 = bf16 ones, rows 1..15 zero
    *(u32*)((char*)vone + tid * 4) = val;
  }
#pragma unroll
  for (int i = 0; i < 2; ++i) {
    int e = i * 512 + tid;
    int row = e >> 3, ch = e & 7;
    uint4 v = *(const uint4*)(qkv + base + (long)(q0 + row) * 1536 + qcol + ch * 8);
    *(uint4*)((char*)q_t + row * 128 + ((ch ^ (row & 7)) << 4)) = v;
  }
  __syncthreads();
  short8 qf[2];
#pragma unroll
  for (int ks = 0; ks < 2; ++ks) {
    int row = w * 16 + lr;
    qf[ks] = *(const short8*)((const char*)q_t + row * 128 + (((ks * 4 + g) ^ (row & 7)) << 4));
  }
  __syncthreads();                               // all waves done with q_t
  stageKV(0, kb0);
  __syncthreads();                               // tile 0 staged (drains vmcnt)

  f32x4 o[5] = {};                               // o[4] = l accumulator (ones-row)

  for (int kt = 0; kt < 16; ++kt) {
    const int cur = kt & 1;
    if (kt + 1 < 16) stageKV(cur ^ 1, kb0 + (kt + 1) * 64);

    // ---- S^T = K Q^T : s[ni][r] = S[key = ni*16+4g+r][q = lr] ----
    f32x4 s[4] = {};
#pragma unroll
    for (int ks = 0; ks < 2; ++ks) {
#pragma unroll
      for (int ni = 0; ni < 4; ++ni) {
        int row = ni * 16 + lr;
        short8 kf = *(const short8*)((const char*)(kv + cur * 4096) + row * 128 + (((ks * 4 + g) ^ (row & 7)) << 4));
        s[ni] = __builtin_amdgcn_mfma_f32_16x16x32_bf16(kf, qf[ks], s[ni], 0, 0, 0);
      }
    }
    // ---- max-free softmax numerator: P = exp2(s*SC + mask) ----
    float p[4][4];
#pragma unroll
    for (int ni = 0; ni < 4; ++ni) {
      const float4 mv = *(const float4*)&mvals[cur][ni * 16 + 4 * g];
      const float mva[4] = {mv.x, mv.y, mv.z, mv.w};
#pragma unroll
      for (int r = 0; r < 4; ++r)
        p[ni][r] = fexp2(fmaf(s[ni][r], SC, mva[r]));
    }
    u32 wv[4][2];
#pragma unroll
    for (int ni = 0; ni < 4; ++ni)
#pragma unroll
      for (int pp = 0; pp < 2; ++pp)
        asm("v_cvt_pk_bf16_f32 %0, %1, %2"
            : "=v"(wv[ni][pp]) : "v"(p[ni][2 * pp]), "v"(p[ni][2 * pp + 1]));

    // ---- in-register redistribution: lane needs P[q=lr][keys 32ks2+8g..+7] ----
    u32 x0 = wv[0][0], x1 = wv[0][1], y0 = wv[1][0], y1 = wv[1][1];
    swap32(x0, y0); swap32(x1, y1);
    swap16(x0, y0, lane); swap16(x1, y1, lane);
    short8 pa0 = mk8((u64)x0 | ((u64)x1 << 32), (u64)y0 | ((u64)y1 << 32));
    u32 x2 = wv[2][0], x3 = wv[2][1], y2 = wv[3][0], y3 = wv[3][1];
    swap32(x2, y2); swap32(x3, y3);
    swap16(x2, y2, lane); swap16(x3, y3, lane);
    short8 pa1 = mk8((u64)x2 | ((u64)x3 << 32), (u64)y2 | ((u64)y3 << 32));

    // ---- O += P V (nd=4 reads the shared ones-block -> l in o[4] at lr==0) ----
#pragma unroll
    for (int ks2 = 0; ks2 < 2; ++ks2) {
      short8 pa = ks2 ? pa1 : pa0;
#pragma unroll
      for (int nd = 0; nd < 5; ++nd) {
        short8 vf;
        if (nd < 4) {
          int vrow = nd * 16 + lr;
          vf = *(const short8*)((const char*)(kv + 8192 + cur * 4096) + vrow * 128 + (((ks2 * 4 + g) ^ (vrow & 7)) << 4));
        } else {
          vf = *(const short8*)((const char*)vone + lr * 128 + (((ks2 * 4 + g) ^ (lr & 7)) << 4));
        }
        o[nd] = __builtin_amdgcn_mfma_f32_16x16x32_bf16(pa, vf, o[nd], 0, 0, 0);
      }
    }
    if (kt + 1 < 16) __syncthreads();
  }
  // ---- epilogue: write UNNORMALIZED partial O (bf16) + partial l ----
  if (lr == 0) {
#pragma unroll
    for (int r = 0; r < 4; ++r) {
      int tok = q0 + w * 16 + 4 * g + r;
      lbuf[(((long)(half * 4 + b)) * 2048 + tok) * 8 + h] = o[4][r];
    }
  }
  u16* dst = half ? o1dst : o0dst;
#pragma unroll
  for (int nd = 0; nd < 4; ++nd)
#pragma unroll
    for (int r = 0; r < 4; ++r) {
      int tok = q0 + w * 16 + 4 * g + r;
      int col = h * 64 + nd * 16 + lr;
      dst[((long)b * S_LEN + tok) * 512 + col] = f2bf(o[nd][r]);
    }
}

// ---------------- attn merge: ctx = (O0 + O1) / (l0 + l1) ----------------
__global__ void attn_merge(const u16* __restrict__ o0, const u16* __restrict__ o1,
                           const float* __restrict__ lbuf, u16* __restrict__ dst) {
  int gid = blockIdx.x * 256 + threadIdx.x;    // NTOK*128 threads
  int tok = gid >> 7, c4 = (gid & 127) << 2;
  int h = c4 >> 6;
  int b = tok >> 11, s = tok & 2047;
  float l1 = lbuf[(((long)b) * 2048 + s) * 8 + h];
  float l2 = lbuf[(((long)(4 + b)) * 2048 + s) * 8 + h];
  float inv = 1.f / (l1 + l2);
  uint2 a = *(const uint2*)(o0 + (long)tok * 512 + c4);
  uint2 c = *(const uint2*)(o1 + (long)tok * 512 + c4);
  float r0 = (bf2f(a.x << 16) + bf2f(c.x << 16)) * inv;
  float r1 = (bf2f(a.x & 0xFFFF0000u) + bf2f(c.x & 0xFFFF0000u)) * inv;
  float r2 = (bf2f(a.y << 16) + bf2f(c.y << 16)) * inv;
  float r3 = (bf2f(a.y & 0xFFFF0000u) + bf2f(c.y & 0xFFFF0000u)) * inv;
  uint2 pk;
  pk.x = (u32)f2bf(r0) | ((u32)f2bf(r1) << 16);
  pk.y = (u32)f2bf(r2) | ((u32)f2bf(r3) << 16);
  *(uint2*)(dst + (long)tok * 512 + c4) = pk;
}

// ---------------- fused residual + layernorm, bf16 residual stream ----------------
template <bool FINAL>
__global__ __launch_bounds__(256) void ln_kernel(const u16* __restrict__ y,
                                                 const u16* __restrict__ res,
                                                 const float* __restrict__ gam,
                                                 const float* __restrict__ bet,
                                                 u16* __restrict__ xout,
                                                 float* __restrict__ outf) {
  const int row = blockIdx.x, t = threadIdx.x;
  const long o0 = (long)row * DM;
  const u32 yb = *(const u32*)(y + o0 + 2 * t);
  const u32 rb = *(const u32*)(res + o0 + 2 * t);
  float a0 = bf2f(yb << 16) + bf2f(rb << 16);
  float a1 = bf2f(yb & 0xFFFF0000u) + bf2f(rb & 0xFFFF0000u);
  float s1 = a0 + a1, s2 = a0 * a0 + a1 * a1;
#pragma unroll
  for (int m = 32; m >= 1; m >>= 1) {
    s1 += __shfl_xor(s1, m);
    s2 += __shfl_xor(s2, m);
  }
  __shared__ float w1[4], w2[4];
  if ((t & 63) == 0) { w1[t >> 6] = s1; w2[t >> 6] = s2; }
  __syncthreads();
  s1 = w1[0] + w1[1] + w1[2] + w1[3];
  s2 = w2[0] + w2[1] + w2[2] + w2[3];
  const float mu = s1 * (1.f / DM);
  const float rstd = rsqrtf(s2 * (1.f / DM) - mu * mu + 1e-5f);
  const float2 gv = *(const float2*)&gam[2 * t];
  const float2 bv = *(const float2*)&bet[2 * t];
  float r0 = (a0 - mu) * rstd * gv.x + bv.x;
  float r1 = (a1 - mu) * rstd * gv.y + bv.y;
  if constexpr (FINAL) {
    float2 ov; ov.x = r0; ov.y = r1;
    *(float2*)&outf[o0 + 2 * t] = ov;
  } else {
    u32 pk = (u32)f2bf(r0) | ((u32)f2bf(r1) << 16);
    *(u32*)&xout[o0 + 2 * t] = pk;
  }
}

extern "C" void kernel_launch(void* const* d_in, const int* in_sizes, int n_in,
                              void* d_out, int out_size, void* d_ws, size_t ws_size,
                              hipStream_t stream) {
  const int*   ids  = (const int*)d_in[0];
  const int*   amsk = (const int*)d_in[1];
  const float* te   = (const float*)d_in[2];
  const float* pe   = (const float*)d_in[3];
  const float* Wq   = (const float*)d_in[4];
  const float* Wk   = (const float*)d_in[5];
  const float* Wv   = (const float*)d_in[6];
  const float* Wo   = (const float*)d_in[7];
  const float* ln1g = (const float*)d_in[8];
  const float* ln1b = (const float*)d_in[9];
  const float* W1   = (const float*)d_in[10];
  const float* W2   = (const float*)d_in[11];
  const float* ln2g = (const float*)d_in[12];
  const float* ln2b = (const float*)d_in[13];
  float* out = (float*)d_out;

  // workspace layout; residual stream x is bf16
  char* p = (char*)d_ws;
  u16* x     = (u16*)p;   p += (long)NTOK * DM * 2;
  u16* qkv   = (u16*)p;   p += (long)NTOK * 1536 * 2;
  u16* ctx   = (u16*)p;   p += (long)NTOK * DM * 2;
  u16* tmp   = (u16*)p;   p += (long)NTOK * DM * 2;
  u16* hb    = (u16*)p;   p += (long)NTOK * 2048 * 2;
  u16* WqkvT = (u16*)p;   p += (long)4 * 1536 * 512 * 2;
  u16* WoT   = (u16*)p;   p += (long)4 * 512 * 512 * 2;
  u16* W1T   = (u16*)p;   p += (long)4 * 2048 * 512 * 2;
  u16* W2T   = (u16*)p;   p += (long)4 * 512 * 2048 * 2;
  float* lbuf = (float*)p; p += (long)2 * B_SZ * S_LEN * 8 * 4;   // [half][b][s][h]
  if ((size_t)(p - (char*)d_ws) > ws_size) return;  // insufficient scratch
  // vt[b][h][d][s] (8 MB) aliases hb: written by QKV GEMM, read by attn, dead before W1.
  u16* vt = hb;

  wconv_all<<<3072, 256, 0, stream>>>(Wq, Wk, Wv, Wo, W1, W2, WqkvT, WoT, W1T, W2T);
  embed_kernel<<<NTOK * 128 / 256, 256, 0, stream>>>(ids, te, pe, x);

  for (int l = 0; l < 4; ++l) {
    // fused QKV projection: [8192,512] @ [512,1536]; BM=256; V -> vt
    gemm_kernel<256, 64, false, true, false><<<dim3(1536 / 64, NTOK / 256), 512, 0, stream>>>(
        x, WqkvT + (long)l * 1536 * 512, qkv, vt, NTOK, 1536, 512);
    // attention: KV-split x2; partial O -> ctx/tmp, partial l -> lbuf
    attn_kernel<<<dim3(S_LEN / 128 * 2, 8, B_SZ), 512, 0, stream>>>(qkv, vt, amsk, ctx, tmp, lbuf);
    // merge into qkv (dead after attn); Wo reads it
    attn_merge<<<NTOK * 128 / 256, 256, 0, stream>>>(ctx, tmp, lbuf, qkv);
    // Wo: SWAPC coalesced C^T epilogue
    gemm_kernel<128, 64, false, false, true><<<dim3(512 / 64, NTOK / 128), 256, 0, stream>>>(
        qkv, WoT + (long)l * 512 * 512, tmp, nullptr, NTOK, 512, 512);
    ln_kernel<false><<<NTOK, 256, 0, stream>>>(tmp, x, ln1g + l * 512, ln1b + l * 512, x, nullptr);
    // W1: BM=256, ReLU, SWAPC
    gemm_kernel<256, 64, true, false, true><<<dim3(2048 / 64, NTOK / 256), 512, 0, stream>>>(
        x, W1T + (long)l * 2048 * 512, hb, nullptr, NTOK, 2048, 512);
    gemm_kernel<128, 64, false, false, true><<<dim3(512 / 64, NTOK / 128), 256, 0, stream>>>(
        hb, W2T + (long)l * 512 * 2048, tmp, nullptr, NTOK, 512, 2048);
    if (l == 3)
      ln_kernel<true><<<NTOK, 256, 0, stream>>>(tmp, x, ln2g + l * 512, ln2b + l * 512, nullptr, out);
    else
      ln_kernel<false><<<NTOK, 256, 0, stream>>>(tmp, x, ln2g + l * 512, ln2b + l * 512, x, nullptr);
  }
}

// Round 15
// 593.435 us; speedup vs baseline: 1.0613x; 1.0613x over previous
//
#include <hip/hip_runtime.h>
#include <stdint.h>

#define S_LEN 2048
#define B_SZ 4
#define DM 512
#define NTOK (B_SZ * S_LEN)

typedef unsigned short u16;
typedef unsigned int u32;
typedef unsigned long long u64;
typedef __attribute__((ext_vector_type(8))) short short8;
typedef __attribute__((ext_vector_type(4))) float f32x4;

typedef const __attribute__((address_space(1))) u32 gq_t;
typedef __attribute__((address_space(3))) u32 lq_t;

__device__ __forceinline__ u16 f2bf(float f) {
  union { float f; u32 u; } v; v.f = f;
  return (u16)((v.u + 0x7FFFu + ((v.u >> 16) & 1u)) >> 16);
}

__device__ __forceinline__ float bf2f(u32 hi16_at_lo) {
  union { u32 u; float f; } v; v.u = hi16_at_lo;
  return v.f;
}

__device__ __forceinline__ float fexp2(float x) {
#if __has_builtin(__builtin_amdgcn_exp2f)
  return __builtin_amdgcn_exp2f(x);
#else
  return exp2f(x);
#endif
}

__device__ __forceinline__ short8 mk8(u64 a, u64 b) {
  union { u64 q[2]; short8 s; } u;
  u.q[0] = a; u.q[1] = b;
  return u.s;
}

// swap X.hi32lanes <-> Y.lo32lanes
__device__ __forceinline__ void swap32(u32& x, u32& y) {
  asm("v_permlane32_swap_b32 %0, %1" : "+v"(x), "+v"(y));
}
// swap lanes16-31 of X with lanes0-15 of Y (per 32-lane block)
__device__ __forceinline__ void swap16(u32& x, u32& y, int lane) {
#if __has_builtin(__builtin_amdgcn_permlane16_swap)
  asm("v_permlane16_swap_b32 %0, %1" : "+v"(x), "+v"(y));
#else
  u32 tx = __builtin_amdgcn_ds_swizzle(x, 0x401F);   // lane^16
  u32 ty = __builtin_amdgcn_ds_swizzle(y, 0x401F);
  bool up = (lane & 16) != 0;
  u32 nx = up ? ty : x;
  u32 ny = up ? y : tx;
  x = nx; y = ny;
#endif
}

// ---------------- embed: x = bf16(tok_embed[ids] + pe) ----------------
__global__ void embed_kernel(const int* __restrict__ ids, const float* __restrict__ te,
                             const float* __restrict__ pe, u16* __restrict__ xb) {
  int gid = blockIdx.x * 256 + threadIdx.x;   // NTOK*128 threads total
  int tok = gid >> 7, c4 = (gid & 127) << 2;
  int s = tok & (S_LEN - 1);
  int id = ids[tok];
  const float4 a = *(const float4*)(te + (long)id * DM + c4);
  const float4 p = *(const float4*)(pe + (long)s * DM + c4);
  uint2 pk;
  pk.x = (u32)f2bf(a.x + p.x) | ((u32)f2bf(a.y + p.y) << 16);
  pk.y = (u32)f2bf(a.z + p.z) | ((u32)f2bf(a.w + p.w) << 16);
  *(uint2*)(xb + (long)tok * DM + c4) = pk;
}

// ------------- weight prep via LDS 64x64 tile transpose (coalesced both sides) -------------
__global__ void wconv_all(const float* __restrict__ Wq, const float* __restrict__ Wk,
                          const float* __restrict__ Wv, const float* __restrict__ Wo,
                          const float* __restrict__ W1, const float* __restrict__ W2,
                          u16* __restrict__ WqkvT, u16* __restrict__ WoT,
                          u16* __restrict__ W1T, u16* __restrict__ W2T) {
  __shared__ u16 t_lds[64 * 65];
  const int tile = blockIdx.x;
  const float* src; u16* dst; int N, K, kt, nt, l;
  if (tile < 768) {                            // Wq|Wk|Wv -> WqkvT panels
    int which = tile >> 8, r = tile & 255;
    l = r >> 6; int rr = r & 63; kt = rr >> 3; nt = rr & 7;
    src = (which == 0 ? Wq : which == 1 ? Wk : Wv) + (long)l * 512 * 512;
    N = 512; K = 512;
    dst = WqkvT + (long)l * 1536 * 512 + (long)(which * 512) * 512;
  } else if (tile < 1024) {                    // Wo
    int r = tile - 768;
    l = r >> 6; int rr = r & 63; kt = rr >> 3; nt = rr & 7;
    src = Wo + (long)l * 512 * 512; N = 512; K = 512;
    dst = WoT + (long)l * 512 * 512;
  } else if (tile < 2048) {                    // W1: K=512, N=2048
    int r = tile - 1024;
    l = r >> 8; int rr = r & 255; kt = rr >> 5; nt = rr & 31;
    src = W1 + (long)l * 512 * 2048; N = 2048; K = 512;
    dst = W1T + (long)l * 2048 * 512;
  } else {                                     // W2: K=2048, N=512
    int r = tile - 2048;
    l = r >> 8; int rr = r & 255; kt = rr >> 3; nt = rr & 7;
    src = W2 + (long)l * 2048 * 512; N = 512; K = 2048;
    dst = W2T + (long)l * 512 * 2048;
  }
  const int tr = threadIdx.x >> 4;
  const int tc = (threadIdx.x & 15) << 2;
#pragma unroll
  for (int i = 0; i < 4; ++i) {
    int k = tr + i * 16;
    const float4 v = *(const float4*)(src + (long)(kt * 64 + k) * N + nt * 64 + tc);
    t_lds[(tc + 0) * 65 + k] = f2bf(v.x);
    t_lds[(tc + 1) * 65 + k] = f2bf(v.y);
    t_lds[(tc + 2) * 65 + k] = f2bf(v.z);
    t_lds[(tc + 3) * 65 + k] = f2bf(v.w);
  }
  __syncthreads();
#pragma unroll
  for (int i = 0; i < 4; ++i) {
    int n = tr + i * 16;
    u16 a0 = t_lds[n * 65 + tc + 0];
    u16 a1 = t_lds[n * 65 + tc + 1];
    u16 a2 = t_lds[n * 65 + tc + 2];
    u16 a3 = t_lds[n * 65 + tc + 3];
    uint2 pk;
    pk.x = (u32)a0 | ((u32)a1 << 16);
    pk.y = (u32)a2 | ((u32)a3 << 16);
    *(uint2*)(dst + (long)(nt * 64 + n) * K + kt * 64 + tc) = pk;
  }
}

// ---------------- GEMM: depth-2 counted-vmcnt + SWAPC + T1 swizzle + T5 setprio ----------------
template <int BM, int BN, bool RELU, bool VSPLIT, bool SWAPC>
__global__ __launch_bounds__(BM * 2) void gemm_kernel(const u16* __restrict__ A,
                                                      const u16* __restrict__ BT,
                                                      void* __restrict__ Cout,
                                                      u16* __restrict__ vt,
                                                      int M, int N, int K) {
  constexpr int NI = BN / 32;
  constexpr int NW = BM / 32;
  constexpr int BRW = BN / NW;
  constexpr int LOADS = 4 + BRW / 8;
  __shared__ __align__(16) u16 a_t[2][BM * 64];
  __shared__ __align__(16) u16 b_t[2][BN * 64];
  const int tid = threadIdx.x;
  const int w = tid >> 6, lane = tid & 63;
  const int wr = w >> 1, wc = w & 1;
  const int g = lane >> 4, lr = lane & 15;
  const int l8 = lane >> 3, lch = lane & 7;
  const int gc = lch ^ l8;
  const int nwg = gridDim.x * gridDim.y;
  const int bid = blockIdx.x + gridDim.x * blockIdx.y;
  const int cpx = nwg >> 3;
  const int swz = (bid & 7) * cpx + (bid >> 3);
  const int bx = swz % gridDim.x, by = swz / gridDim.x;
  const long m0 = (long)by * BM, n0 = (long)bx * BN;
  f32x4 acc[4][NI] = {};
  const int nk = K >> 6;

  auto stage = [&](int nb, int kt) {
    const int k0 = kt << 6;
#pragma unroll
    for (int i = 0; i < 4; ++i) {
      int row = w * 32 + i * 8 + l8;
      __builtin_amdgcn_global_load_lds((gq_t*)(A + (m0 + row) * K + k0 + gc * 8),
                                       (lq_t*)&a_t[nb][(w * 4 + i) * 512], 16, 0, 0);
    }
#pragma unroll
    for (int i = 0; i < BRW / 8; ++i) {
      int row = w * BRW + i * 8 + l8;
      __builtin_amdgcn_global_load_lds((gq_t*)(BT + (n0 + row) * K + k0 + gc * 8),
                                       (lq_t*)&b_t[nb][(w * (BRW / 8) + i) * 512], 16, 0, 0);
    }
  };

  stage(0, 0);
  stage(1, 1);
  for (int kt = 0; kt < nk; ++kt) {
    const int cur = kt & 1;
    if (kt + 1 < nk) {
      if constexpr (LOADS == 6) asm volatile("s_waitcnt vmcnt(6)" ::: "memory");
      else                      asm volatile("s_waitcnt vmcnt(5)" ::: "memory");
    } else {
      asm volatile("s_waitcnt vmcnt(0)" ::: "memory");
    }
    __builtin_amdgcn_s_barrier();
    __builtin_amdgcn_sched_barrier(0);
    short8 af[2][4], bfr[2][NI];
#pragma unroll
    for (int ks = 0; ks < 2; ++ks) {
#pragma unroll
      for (int mi = 0; mi < 4; ++mi) {
        int row = wr * 64 + mi * 16 + lr;
        int byte = row * 128 + (((ks * 4 + g) ^ (row & 7)) << 4);
        af[ks][mi] = *(const short8*)((const char*)a_t[cur] + byte);
      }
#pragma unroll
      for (int ni = 0; ni < NI; ++ni) {
        int row = wc * (BN / 2) + ni * 16 + lr;
        int byte = row * 128 + (((ks * 4 + g) ^ (row & 7)) << 4);
        bfr[ks][ni] = *(const short8*)((const char*)b_t[cur] + byte);
      }
    }
    asm volatile("s_waitcnt lgkmcnt(0)" ::: "memory");
    __builtin_amdgcn_s_barrier();
    __builtin_amdgcn_sched_barrier(0);
    if (kt + 2 < nk) stage(cur, kt + 2);
    __builtin_amdgcn_s_setprio(1);
#pragma unroll
    for (int ks = 0; ks < 2; ++ks)
#pragma unroll
      for (int mi = 0; mi < 4; ++mi)
#pragma unroll
        for (int ni = 0; ni < NI; ++ni) {
          if constexpr (SWAPC)
            acc[mi][ni] = __builtin_amdgcn_mfma_f32_16x16x32_bf16(bfr[ks][ni], af[ks][mi], acc[mi][ni], 0, 0, 0);
          else
            acc[mi][ni] = __builtin_amdgcn_mfma_f32_16x16x32_bf16(af[ks][mi], bfr[ks][ni], acc[mi][ni], 0, 0, 0);
        }
    __builtin_amdgcn_s_setprio(0);
  }

  if constexpr (VSPLIT) {
    if (n0 >= 1024) {
#pragma unroll
      for (int mi = 0; mi < 4; ++mi)
#pragma unroll
        for (int ni = 0; ni < NI; ++ni) {
          int vc = (int)(n0 - 1024) + wc * (BN / 2) + ni * 16 + lr;   // h*64 + d
          int hh = vc >> 6, d = vc & 63;
          long tok0 = m0 + wr * 64 + mi * 16 + g * 4;
          int bb = (int)(tok0 >> 11), s0 = (int)(tok0 & 2047);
          uint2 pk;
          pk.x = (u32)f2bf(acc[mi][ni][0]) | ((u32)f2bf(acc[mi][ni][1]) << 16);
          pk.y = (u32)f2bf(acc[mi][ni][2]) | ((u32)f2bf(acc[mi][ni][3]) << 16);
          *(uint2*)(vt + (((long)bb * 8 + hh) * 64 + d) * 2048 + s0) = pk;
        }
      return;
    }
  }
  if constexpr (SWAPC) {
#pragma unroll
    for (int mi = 0; mi < 4; ++mi)
#pragma unroll
      for (int ni = 0; ni < NI; ++ni) {
        long grow = m0 + wr * 64 + mi * 16 + lr;
        long gcb = n0 + wc * (BN / 2) + ni * 16 + 4 * g;
        float v0 = acc[mi][ni][0], v1 = acc[mi][ni][1], v2 = acc[mi][ni][2], v3 = acc[mi][ni][3];
        if (RELU) {
          v0 = fmaxf(v0, 0.f); v1 = fmaxf(v1, 0.f); v2 = fmaxf(v2, 0.f); v3 = fmaxf(v3, 0.f);
        }
        uint2 pk;
        pk.x = (u32)f2bf(v0) | ((u32)f2bf(v1) << 16);
        pk.y = (u32)f2bf(v2) | ((u32)f2bf(v3) << 16);
        *(uint2*)((u16*)Cout + grow * N + gcb) = pk;
      }
  } else {
#pragma unroll
    for (int mi = 0; mi < 4; ++mi)
#pragma unroll
      for (int ni = 0; ni < NI; ++ni)
#pragma unroll
        for (int j = 0; j < 4; ++j) {
          long grow = m0 + wr * 64 + mi * 16 + g * 4 + j;
          long gcol = n0 + wc * (BN / 2) + ni * 16 + lr;
          float v = acc[mi][ni][j];
          if (RELU) v = fmaxf(v, 0.f);
          ((u16*)Cout)[grow * N + gcol] = f2bf(v);
        }
  }
}

// ---------------- flash attention (round-13 single-pass + LDS trim + setprio) ----------------
// block = (b, h, 128-query tile), 8 waves x 16 q; swapped QK^T, MAX-FREE softmax, row-sum
// via matrix pipe (shared ones-block), K/V dbuf via global_load_lds, one barrier/tile,
// in-register P redistribution. q_t aliases k_t (dead after prologue); LDS ~35KB.
__global__ __launch_bounds__(512) void attn_kernel(const u16* __restrict__ qkv,
                                                   const u16* __restrict__ vt,
                                                   const int* __restrict__ mask,
                                                   u16* __restrict__ ctx) {
  __shared__ __align__(16) u16 kv[2 * 4096 + 2 * 4096 + 1024];  // k_t[2] | v_t[2] | vone
  __shared__ __align__(16) float mvals[2][64];
  __shared__ __align__(16) float l_lds[128];
  const int tid = threadIdx.x;
  const int w = tid >> 6, lane = tid & 63;
  const int g = lane >> 4, lr = lane & 15;
  const int l8 = lane >> 3, lch = lane & 7;
  const int gc = lch ^ l8;
  const int b = blockIdx.z, h = blockIdx.y, q0 = blockIdx.x * 128;
  const long base = (long)b * S_LEN * 1536;
  const int qcol = h * 64, kcol = 512 + h * 64;
  const u16* vhead = vt + (((long)b * 8 + h) * 64) * 2048;
  u16* q_t = kv;                                 // aliases k_t[0..1]; prologue only
  u16* vone = kv + 16384;
  const float SC = 0.18033688011112042f;         // 0.125 * log2(e)

  auto stageKV = [&](int nb, int kb) {
    int row = w * 8 + l8;
    __builtin_amdgcn_global_load_lds((gq_t*)(qkv + base + (long)(kb + row) * 1536 + kcol + gc * 8),
                                     (lq_t*)(kv + nb * 4096 + w * 512), 16, 0, 0);
    __builtin_amdgcn_global_load_lds((gq_t*)(vhead + (long)row * 2048 + kb + gc * 8),
                                     (lq_t*)(kv + 8192 + nb * 4096 + w * 512), 16, 0, 0);
    if (tid < 64) mvals[nb][tid] = (mask[b * S_LEN + kb + tid] == 0) ? -1e9f : 0.f;
  };

  // ---- prologue: vone init + Q stage (aliased region) -> qf -> KV tile 0 ----
  {
    u32 val = ((tid >> 5) == 0) ? 0x3F803F80u : 0u;   // row 0 = bf16 ones, rows 1..15 zero
    *(u32*)((char*)vone + tid * 4) = val;
  }
#pragma unroll
  for (int i = 0; i < 2; ++i) {
    int e = i * 512 + tid;
    int row = e >> 3, ch = e & 7;
    uint4 v = *(const uint4*)(qkv + base + (long)(q0 + row) * 1536 + qcol + ch * 8);
    *(uint4*)((char*)q_t + row * 128 + ((ch ^ (row & 7)) << 4)) = v;
  }
  __syncthreads();
  short8 qf[2];
#pragma unroll
  for (int ks = 0; ks < 2; ++ks) {
    int row = w * 16 + lr;
    qf[ks] = *(const short8*)((const char*)q_t + row * 128 + (((ks * 4 + g) ^ (row & 7)) << 4));
  }
  __syncthreads();                               // all waves done with q_t
  stageKV(0, 0);
  __syncthreads();                               // tile 0 staged

  f32x4 o[5] = {};                               // o[4] = l accumulator (ones-row)

  for (int kt = 0; kt < S_LEN / 64; ++kt) {
    const int cur = kt & 1;
    if (kt + 1 < S_LEN / 64) stageKV(cur ^ 1, (kt + 1) * 64);

    // ---- S^T = K Q^T : s[ni][r] = S[key = ni*16+4g+r][q = lr] ----
    f32x4 s[4] = {};
    __builtin_amdgcn_s_setprio(1);
#pragma unroll
    for (int ks = 0; ks < 2; ++ks) {
#pragma unroll
      for (int ni = 0; ni < 4; ++ni) {
        int row = ni * 16 + lr;
        short8 kf = *(const short8*)((const char*)(kv + cur * 4096) + row * 128 + (((ks * 4 + g) ^ (row & 7)) << 4));
        s[ni] = __builtin_amdgcn_mfma_f32_16x16x32_bf16(kf, qf[ks], s[ni], 0, 0, 0);
      }
    }
    __builtin_amdgcn_s_setprio(0);
    // ---- max-free softmax numerator: P = exp2(s*SC + mask) ----
    float p[4][4];
#pragma unroll
    for (int ni = 0; ni < 4; ++ni) {
      const float4 mv = *(const float4*)&mvals[cur][ni * 16 + 4 * g];
      const float mva[4] = {mv.x, mv.y, mv.z, mv.w};
#pragma unroll
      for (int r = 0; r < 4; ++r)
        p[ni][r] = fexp2(fmaf(s[ni][r], SC, mva[r]));
    }
    u32 wv[4][2];
#pragma unroll
    for (int ni = 0; ni < 4; ++ni)
#pragma unroll
      for (int pp = 0; pp < 2; ++pp)
        asm("v_cvt_pk_bf16_f32 %0, %1, %2"
            : "=v"(wv[ni][pp]) : "v"(p[ni][2 * pp]), "v"(p[ni][2 * pp + 1]));

    // ---- in-register redistribution: lane needs P[q=lr][keys 32ks2+8g..+7] ----
    u32 x0 = wv[0][0], x1 = wv[0][1], y0 = wv[1][0], y1 = wv[1][1];
    swap32(x0, y0); swap32(x1, y1);
    swap16(x0, y0, lane); swap16(x1, y1, lane);
    short8 pa0 = mk8((u64)x0 | ((u64)x1 << 32), (u64)y0 | ((u64)y1 << 32));
    u32 x2 = wv[2][0], x3 = wv[2][1], y2 = wv[3][0], y3 = wv[3][1];
    swap32(x2, y2); swap32(x3, y3);
    swap16(x2, y2, lane); swap16(x3, y3, lane);
    short8 pa1 = mk8((u64)x2 | ((u64)x3 << 32), (u64)y2 | ((u64)y3 << 32));

    // ---- O += P V (nd=4 reads the shared ones-block -> l in o[4] at lr==0) ----
    __builtin_amdgcn_s_setprio(1);
#pragma unroll
    for (int ks2 = 0; ks2 < 2; ++ks2) {
      short8 pa = ks2 ? pa1 : pa0;
#pragma unroll
      for (int nd = 0; nd < 5; ++nd) {
        short8 vf;
        if (nd < 4) {
          int vrow = nd * 16 + lr;
          vf = *(const short8*)((const char*)(kv + 8192 + cur * 4096) + vrow * 128 + (((ks2 * 4 + g) ^ (vrow & 7)) << 4));
        } else {
          vf = *(const short8*)((const char*)vone + lr * 128 + (((ks2 * 4 + g) ^ (lr & 7)) << 4));
        }
        o[nd] = __builtin_amdgcn_mfma_f32_16x16x32_bf16(pa, vf, o[nd], 0, 0, 0);
      }
    }
    __builtin_amdgcn_s_setprio(0);
    if (kt + 1 < S_LEN / 64) __syncthreads();
  }
  // ---- epilogue: l lives in o[4][r] at lanes lr==0 ----
  if (lr == 0) {
#pragma unroll
    for (int r = 0; r < 4; ++r) l_lds[w * 16 + 4 * g + r] = o[4][r];
  }
  const float4 lv = *(const float4*)&l_lds[w * 16 + 4 * g];
  const float la[4] = {lv.x, lv.y, lv.z, lv.w};
  float inv[4];
#pragma unroll
  for (int r = 0; r < 4; ++r) inv[r] = 1.f / la[r];
#pragma unroll
  for (int nd = 0; nd < 4; ++nd)
#pragma unroll
    for (int r = 0; r < 4; ++r) {
      int tok = q0 + w * 16 + 4 * g + r;
      int col = h * 64 + nd * 16 + lr;
      ctx[((long)b * S_LEN + tok) * 512 + col] = f2bf(o[nd][r] * inv[r]);
    }
}

// ---------------- fused residual + layernorm, bf16 residual stream ----------------
template <bool FINAL>
__global__ __launch_bounds__(256) void ln_kernel(const u16* __restrict__ y,
                                                 const u16* __restrict__ res,
                                                 const float* __restrict__ gam,
                                                 const float* __restrict__ bet,
                                                 u16* __restrict__ xout,
                                                 float* __restrict__ outf) {
  const int row = blockIdx.x, t = threadIdx.x;
  const long o0 = (long)row * DM;
  const u32 yb = *(const u32*)(y + o0 + 2 * t);
  const u32 rb = *(const u32*)(res + o0 + 2 * t);
  float a0 = bf2f(yb << 16) + bf2f(rb << 16);
  float a1 = bf2f(yb & 0xFFFF0000u) + bf2f(rb & 0xFFFF0000u);
  float s1 = a0 + a1, s2 = a0 * a0 + a1 * a1;
#pragma unroll
  for (int m = 32; m >= 1; m >>= 1) {
    s1 += __shfl_xor(s1, m);
    s2 += __shfl_xor(s2, m);
  }
  __shared__ float w1[4], w2[4];
  if ((t & 63) == 0) { w1[t >> 6] = s1; w2[t >> 6] = s2; }
  __syncthreads();
  s1 = w1[0] + w1[1] + w1[2] + w1[3];
  s2 = w2[0] + w2[1] + w2[2] + w2[3];
  const float mu = s1 * (1.f / DM);
  const float rstd = rsqrtf(s2 * (1.f / DM) - mu * mu + 1e-5f);
  const float2 gv = *(const float2*)&gam[2 * t];
  const float2 bv = *(const float2*)&bet[2 * t];
  float r0 = (a0 - mu) * rstd * gv.x + bv.x;
  float r1 = (a1 - mu) * rstd * gv.y + bv.y;
  if constexpr (FINAL) {
    float2 ov; ov.x = r0; ov.y = r1;
    *(float2*)&outf[o0 + 2 * t] = ov;
  } else {
    u32 pk = (u32)f2bf(r0) | ((u32)f2bf(r1) << 16);
    *(u32*)&xout[o0 + 2 * t] = pk;
  }
}

extern "C" void kernel_launch(void* const* d_in, const int* in_sizes, int n_in,
                              void* d_out, int out_size, void* d_ws, size_t ws_size,
                              hipStream_t stream) {
  const int*   ids  = (const int*)d_in[0];
  const int*   amsk = (const int*)d_in[1];
  const float* te   = (const float*)d_in[2];
  const float* pe   = (const float*)d_in[3];
  const float* Wq   = (const float*)d_in[4];
  const float* Wk   = (const float*)d_in[5];
  const float* Wv   = (const float*)d_in[6];
  const float* Wo   = (const float*)d_in[7];
  const float* ln1g = (const float*)d_in[8];
  const float* ln1b = (const float*)d_in[9];
  const float* W1   = (const float*)d_in[10];
  const float* W2   = (const float*)d_in[11];
  const float* ln2g = (const float*)d_in[12];
  const float* ln2b = (const float*)d_in[13];
  float* out = (float*)d_out;

  // workspace layout; residual stream x is bf16
  char* p = (char*)d_ws;
  u16* x     = (u16*)p;   p += (long)NTOK * DM * 2;
  u16* qkv   = (u16*)p;   p += (long)NTOK * 1536 * 2;
  u16* ctx   = (u16*)p;   p += (long)NTOK * DM * 2;
  u16* tmp   = (u16*)p;   p += (long)NTOK * DM * 2;
  u16* hb    = (u16*)p;   p += (long)NTOK * 2048 * 2;
  u16* WqkvT = (u16*)p;   p += (long)4 * 1536 * 512 * 2;
  u16* WoT   = (u16*)p;   p += (long)4 * 512 * 512 * 2;
  u16* W1T   = (u16*)p;   p += (long)4 * 2048 * 512 * 2;
  u16* W2T   = (u16*)p;   p += (long)4 * 512 * 2048 * 2;
  if ((size_t)(p - (char*)d_ws) > ws_size) return;  // insufficient scratch
  // vt[b][h][d][s] (8 MB) aliases hb: written by QKV GEMM, read by attn, dead before W1.
  u16* vt = hb;

  wconv_all<<<3072, 256, 0, stream>>>(Wq, Wk, Wv, Wo, W1, W2, WqkvT, WoT, W1T, W2T);
  embed_kernel<<<NTOK * 128 / 256, 256, 0, stream>>>(ids, te, pe, x);

  for (int l = 0; l < 4; ++l) {
    // fused QKV projection: [8192,512] @ [512,1536]; BM=256; V -> vt
    gemm_kernel<256, 64, false, true, false><<<dim3(1536 / 64, NTOK / 256), 512, 0, stream>>>(
        x, WqkvT + (long)l * 1536 * 512, qkv, vt, NTOK, 1536, 512);
    attn_kernel<<<dim3(S_LEN / 128, 8, B_SZ), 512, 0, stream>>>(qkv, vt, amsk, ctx);
    // Wo: SWAPC coalesced C^T epilogue
    gemm_kernel<128, 64, false, false, true><<<dim3(512 / 64, NTOK / 128), 256, 0, stream>>>(
        ctx, WoT + (long)l * 512 * 512, tmp, nullptr, NTOK, 512, 512);
    ln_kernel<false><<<NTOK, 256, 0, stream>>>(tmp, x, ln1g + l * 512, ln1b + l * 512, x, nullptr);
    // W1: BM=256, ReLU, SWAPC
    gemm_kernel<256, 64, true, false, true><<<dim3(2048 / 64, NTOK / 256), 512, 0, stream>>>(
        x, W1T + (long)l * 2048 * 512, hb, nullptr, NTOK, 2048, 512);
    gemm_kernel<128, 64, false, false, true><<<dim3(512 / 64, NTOK / 128), 256, 0, stream>>>(
        hb, W2T + (long)l * 512 * 2048, tmp, nullptr, NTOK, 512, 2048);
    if (l == 3)
      ln_kernel<true><<<NTOK, 256, 0, stream>>>(tmp, x, ln2g + l * 512, ln2b + l * 512, nullptr, out);
    else
      ln_kernel<false><<<NTOK, 256, 0, stream>>>(tmp, x, ln2g + l * 512, ln2b + l * 512, x, nullptr);
  }
}

// Round 16
// 559.723 us; speedup vs baseline: 1.1252x; 1.0602x over previous
//
#include <hip/hip_runtime.h>
#include <stdint.h>

#define S_LEN 2048
#define B_SZ 4
#define DM 512
#define NTOK (B_SZ * S_LEN)

typedef unsigned short u16;
typedef unsigned int u32;
typedef unsigned long long u64;
typedef __attribute__((ext_vector_type(8))) short short8;
typedef __attribute__((ext_vector_type(4))) float f32x4;

typedef const __attribute__((address_space(1))) u32 gq_t;
typedef __attribute__((address_space(3))) u32 lq_t;

__device__ __forceinline__ u16 f2bf(float f) {
  union { float f; u32 u; } v; v.f = f;
  return (u16)((v.u + 0x7FFFu + ((v.u >> 16) & 1u)) >> 16);
}

__device__ __forceinline__ float bf2f(u32 hi16_at_lo) {
  union { u32 u; float f; } v; v.u = hi16_at_lo;
  return v.f;
}

__device__ __forceinline__ float fexp2(float x) {
#if __has_builtin(__builtin_amdgcn_exp2f)
  return __builtin_amdgcn_exp2f(x);
#else
  return exp2f(x);
#endif
}

__device__ __forceinline__ short8 mk8(u64 a, u64 b) {
  union { u64 q[2]; short8 s; } u;
  u.q[0] = a; u.q[1] = b;
  return u.s;
}

// swap X.hi32lanes <-> Y.lo32lanes
__device__ __forceinline__ void swap32(u32& x, u32& y) {
  asm("v_permlane32_swap_b32 %0, %1" : "+v"(x), "+v"(y));
}
// swap lanes16-31 of X with lanes0-15 of Y (per 32-lane block)
__device__ __forceinline__ void swap16(u32& x, u32& y, int lane) {
#if __has_builtin(__builtin_amdgcn_permlane16_swap)
  asm("v_permlane16_swap_b32 %0, %1" : "+v"(x), "+v"(y));
#else
  u32 tx = __builtin_amdgcn_ds_swizzle(x, 0x401F);   // lane^16
  u32 ty = __builtin_amdgcn_ds_swizzle(y, 0x401F);
  bool up = (lane & 16) != 0;
  u32 nx = up ? ty : x;
  u32 ny = up ? y : tx;
  x = nx; y = ny;
#endif
}

// ---------------- key compaction: per batch, ordered list of valid key positions ----------------
// cidx[b][j] = s of j-th valid key; cmap[b][s] = compact pos or -1; nvalid[b] = count.
__global__ void compact_kernel(const int* __restrict__ mask, int* __restrict__ cidx,
                               int* __restrict__ cmap, int* __restrict__ nvalid) {
  __shared__ int wcnt[4];
  __shared__ int running;
  const int b = blockIdx.x, tid = threadIdx.x;   // 256 threads, 4 waves
  if (tid == 0) running = 0;
  __syncthreads();
  for (int c = 0; c < 8; ++c) {
    int s = c * 256 + tid;
    int valid = (mask[b * 2048 + s] != 0) ? 1 : 0;
    u64 bal = __ballot(valid);
    int lane = tid & 63, wv = tid >> 6;
    int pre = __popcll(bal & ((1ULL << lane) - 1ULL));
    if (lane == 0) wcnt[wv] = __popcll(bal);
    __syncthreads();
    int woff = running;
    for (int j = 0; j < wv; ++j) woff += wcnt[j];
    int pos = woff + pre;
    if (valid) {
      cidx[b * 2048 + pos] = s;
      cmap[b * 2048 + s] = pos;
    } else {
      cmap[b * 2048 + s] = -1;
    }
    __syncthreads();
    if (tid == 0) running += wcnt[0] + wcnt[1] + wcnt[2] + wcnt[3];
    __syncthreads();
  }
  if (tid == 0) nvalid[b] = running;
}

// ---------------- embed: x = bf16(tok_embed[ids] + pe) ----------------
__global__ void embed_kernel(const int* __restrict__ ids, const float* __restrict__ te,
                             const float* __restrict__ pe, u16* __restrict__ xb) {
  int gid = blockIdx.x * 256 + threadIdx.x;   // NTOK*128 threads total
  int tok = gid >> 7, c4 = (gid & 127) << 2;
  int s = tok & (S_LEN - 1);
  int id = ids[tok];
  const float4 a = *(const float4*)(te + (long)id * DM + c4);
  const float4 p = *(const float4*)(pe + (long)s * DM + c4);
  uint2 pk;
  pk.x = (u32)f2bf(a.x + p.x) | ((u32)f2bf(a.y + p.y) << 16);
  pk.y = (u32)f2bf(a.z + p.z) | ((u32)f2bf(a.w + p.w) << 16);
  *(uint2*)(xb + (long)tok * DM + c4) = pk;
}

// ------------- weight prep via LDS 64x64 tile transpose (coalesced both sides) -------------
__global__ void wconv_all(const float* __restrict__ Wq, const float* __restrict__ Wk,
                          const float* __restrict__ Wv, const float* __restrict__ Wo,
                          const float* __restrict__ W1, const float* __restrict__ W2,
                          u16* __restrict__ WqkvT, u16* __restrict__ WoT,
                          u16* __restrict__ W1T, u16* __restrict__ W2T) {
  __shared__ u16 t_lds[64 * 65];
  const int tile = blockIdx.x;
  const float* src; u16* dst; int N, K, kt, nt, l;
  if (tile < 768) {                            // Wq|Wk|Wv -> WqkvT panels
    int which = tile >> 8, r = tile & 255;
    l = r >> 6; int rr = r & 63; kt = rr >> 3; nt = rr & 7;
    src = (which == 0 ? Wq : which == 1 ? Wk : Wv) + (long)l * 512 * 512;
    N = 512; K = 512;
    dst = WqkvT + (long)l * 1536 * 512 + (long)(which * 512) * 512;
  } else if (tile < 1024) {                    // Wo
    int r = tile - 768;
    l = r >> 6; int rr = r & 63; kt = rr >> 3; nt = rr & 7;
    src = Wo + (long)l * 512 * 512; N = 512; K = 512;
    dst = WoT + (long)l * 512 * 512;
  } else if (tile < 2048) {                    // W1: K=512, N=2048
    int r = tile - 1024;
    l = r >> 8; int rr = r & 255; kt = rr >> 5; nt = rr & 31;
    src = W1 + (long)l * 512 * 2048; N = 2048; K = 512;
    dst = W1T + (long)l * 2048 * 512;
  } else {                                     // W2: K=2048, N=512
    int r = tile - 2048;
    l = r >> 8; int rr = r & 255; kt = rr >> 3; nt = rr & 7;
    src = W2 + (long)l * 2048 * 512; N = 512; K = 2048;
    dst = W2T + (long)l * 512 * 2048;
  }
  const int tr = threadIdx.x >> 4;
  const int tc = (threadIdx.x & 15) << 2;
#pragma unroll
  for (int i = 0; i < 4; ++i) {
    int k = tr + i * 16;
    const float4 v = *(const float4*)(src + (long)(kt * 64 + k) * N + nt * 64 + tc);
    t_lds[(tc + 0) * 65 + k] = f2bf(v.x);
    t_lds[(tc + 1) * 65 + k] = f2bf(v.y);
    t_lds[(tc + 2) * 65 + k] = f2bf(v.z);
    t_lds[(tc + 3) * 65 + k] = f2bf(v.w);
  }
  __syncthreads();
#pragma unroll
  for (int i = 0; i < 4; ++i) {
    int n = tr + i * 16;
    u16 a0 = t_lds[n * 65 + tc + 0];
    u16 a1 = t_lds[n * 65 + tc + 1];
    u16 a2 = t_lds[n * 65 + tc + 2];
    u16 a3 = t_lds[n * 65 + tc + 3];
    uint2 pk;
    pk.x = (u32)a0 | ((u32)a1 << 16);
    pk.y = (u32)a2 | ((u32)a3 << 16);
    *(uint2*)(dst + (long)(nt * 64 + n) * K + kt * 64 + tc) = pk;
  }
}

// ---------------- GEMM: depth-2 counted-vmcnt + SWAPC + T1 swizzle + T5 setprio ----------------
// VSPLIT: V columns written transposed AND key-compacted: vt[b][h][d][cmap[tok]] (valid only).
template <int BM, int BN, bool RELU, bool VSPLIT, bool SWAPC>
__global__ __launch_bounds__(BM * 2) void gemm_kernel(const u16* __restrict__ A,
                                                      const u16* __restrict__ BT,
                                                      void* __restrict__ Cout,
                                                      u16* __restrict__ vt,
                                                      const int* __restrict__ cmap,
                                                      int M, int N, int K) {
  constexpr int NI = BN / 32;
  constexpr int NW = BM / 32;
  constexpr int BRW = BN / NW;
  constexpr int LOADS = 4 + BRW / 8;
  __shared__ __align__(16) u16 a_t[2][BM * 64];
  __shared__ __align__(16) u16 b_t[2][BN * 64];
  const int tid = threadIdx.x;
  const int w = tid >> 6, lane = tid & 63;
  const int wr = w >> 1, wc = w & 1;
  const int g = lane >> 4, lr = lane & 15;
  const int l8 = lane >> 3, lch = lane & 7;
  const int gc = lch ^ l8;
  const int nwg = gridDim.x * gridDim.y;
  const int bid = blockIdx.x + gridDim.x * blockIdx.y;
  const int cpx = nwg >> 3;
  const int swz = (bid & 7) * cpx + (bid >> 3);
  const int bx = swz % gridDim.x, by = swz / gridDim.x;
  const long m0 = (long)by * BM, n0 = (long)bx * BN;
  f32x4 acc[4][NI] = {};
  const int nk = K >> 6;

  auto stage = [&](int nb, int kt) {
    const int k0 = kt << 6;
#pragma unroll
    for (int i = 0; i < 4; ++i) {
      int row = w * 32 + i * 8 + l8;
      __builtin_amdgcn_global_load_lds((gq_t*)(A + (m0 + row) * K + k0 + gc * 8),
                                       (lq_t*)&a_t[nb][(w * 4 + i) * 512], 16, 0, 0);
    }
#pragma unroll
    for (int i = 0; i < BRW / 8; ++i) {
      int row = w * BRW + i * 8 + l8;
      __builtin_amdgcn_global_load_lds((gq_t*)(BT + (n0 + row) * K + k0 + gc * 8),
                                       (lq_t*)&b_t[nb][(w * (BRW / 8) + i) * 512], 16, 0, 0);
    }
  };

  stage(0, 0);
  stage(1, 1);
  for (int kt = 0; kt < nk; ++kt) {
    const int cur = kt & 1;
    if (kt + 1 < nk) {
      if constexpr (LOADS == 6) asm volatile("s_waitcnt vmcnt(6)" ::: "memory");
      else                      asm volatile("s_waitcnt vmcnt(5)" ::: "memory");
    } else {
      asm volatile("s_waitcnt vmcnt(0)" ::: "memory");
    }
    __builtin_amdgcn_s_barrier();
    __builtin_amdgcn_sched_barrier(0);
    short8 af[2][4], bfr[2][NI];
#pragma unroll
    for (int ks = 0; ks < 2; ++ks) {
#pragma unroll
      for (int mi = 0; mi < 4; ++mi) {
        int row = wr * 64 + mi * 16 + lr;
        int byte = row * 128 + (((ks * 4 + g) ^ (row & 7)) << 4);
        af[ks][mi] = *(const short8*)((const char*)a_t[cur] + byte);
      }
#pragma unroll
      for (int ni = 0; ni < NI; ++ni) {
        int row = wc * (BN / 2) + ni * 16 + lr;
        int byte = row * 128 + (((ks * 4 + g) ^ (row & 7)) << 4);
        bfr[ks][ni] = *(const short8*)((const char*)b_t[cur] + byte);
      }
    }
    asm volatile("s_waitcnt lgkmcnt(0)" ::: "memory");
    __builtin_amdgcn_s_barrier();
    __builtin_amdgcn_sched_barrier(0);
    if (kt + 2 < nk) stage(cur, kt + 2);
    __builtin_amdgcn_s_setprio(1);
#pragma unroll
    for (int ks = 0; ks < 2; ++ks)
#pragma unroll
      for (int mi = 0; mi < 4; ++mi)
#pragma unroll
        for (int ni = 0; ni < NI; ++ni) {
          if constexpr (SWAPC)
            acc[mi][ni] = __builtin_amdgcn_mfma_f32_16x16x32_bf16(bfr[ks][ni], af[ks][mi], acc[mi][ni], 0, 0, 0);
          else
            acc[mi][ni] = __builtin_amdgcn_mfma_f32_16x16x32_bf16(af[ks][mi], bfr[ks][ni], acc[mi][ni], 0, 0, 0);
        }
    __builtin_amdgcn_s_setprio(0);
  }

  if constexpr (VSPLIT) {
    if (n0 >= 1024) {
      // V block: write transposed + compacted. Only valid tokens (cmap >= 0).
#pragma unroll
      for (int mi = 0; mi < 4; ++mi) {
        long tok0 = m0 + wr * 64 + mi * 16 + g * 4;
#pragma unroll
        for (int j = 0; j < 4; ++j) {
          int cs = cmap[tok0 + j];
          if (cs < 0) continue;
          int bb = (int)((tok0 + j) >> 11);
#pragma unroll
          for (int ni = 0; ni < NI; ++ni) {
            int vc = (int)(n0 - 1024) + wc * (BN / 2) + ni * 16 + lr;   // h*64 + d
            int hh = vc >> 6, d = vc & 63;
            vt[(((long)bb * 8 + hh) * 64 + d) * 2048 + cs] = f2bf(acc[mi][ni][j]);
          }
        }
      }
      return;
    }
  }
  if constexpr (SWAPC) {
#pragma unroll
    for (int mi = 0; mi < 4; ++mi)
#pragma unroll
      for (int ni = 0; ni < NI; ++ni) {
        long grow = m0 + wr * 64 + mi * 16 + lr;
        long gcb = n0 + wc * (BN / 2) + ni * 16 + 4 * g;
        float v0 = acc[mi][ni][0], v1 = acc[mi][ni][1], v2 = acc[mi][ni][2], v3 = acc[mi][ni][3];
        if (RELU) {
          v0 = fmaxf(v0, 0.f); v1 = fmaxf(v1, 0.f); v2 = fmaxf(v2, 0.f); v3 = fmaxf(v3, 0.f);
        }
        uint2 pk;
        pk.x = (u32)f2bf(v0) | ((u32)f2bf(v1) << 16);
        pk.y = (u32)f2bf(v2) | ((u32)f2bf(v3) << 16);
        *(uint2*)((u16*)Cout + grow * N + gcb) = pk;
      }
  } else {
#pragma unroll
    for (int mi = 0; mi < 4; ++mi)
#pragma unroll
      for (int ni = 0; ni < NI; ++ni)
#pragma unroll
        for (int j = 0; j < 4; ++j) {
          long grow = m0 + wr * 64 + mi * 16 + g * 4 + j;
          long gcol = n0 + wc * (BN / 2) + ni * 16 + lr;
          float v = acc[mi][ni][j];
          if (RELU) v = fmaxf(v, 0.f);
          ((u16*)Cout)[grow * N + gcol] = f2bf(v);
        }
  }
}

// ---------------- flash attention over COMPACTED keys ----------------
// block = (b, h, 128-query tile), 8 waves x 16 q; loops ceil(nvalid[b]/64) tiles (~half of 32).
// K gathered via per-lane indirect rows (cidx); V pre-compacted in vt. Tail slots get
// mvals=-1e9 -> P=0 (garbage V contributes 0). Max-free softmax, matrix-pipe row-sum,
// dbuf global_load_lds, setprio on MFMA clusters.
__global__ __launch_bounds__(512) void attn_kernel(const u16* __restrict__ qkv,
                                                   const u16* __restrict__ vt,
                                                   const int* __restrict__ cidx,
                                                   const int* __restrict__ nvalid,
                                                   u16* __restrict__ ctx) {
  __shared__ __align__(16) u16 kv[2 * 4096 + 2 * 4096 + 1024];  // k_t[2] | v_t[2] | vone
  __shared__ __align__(16) float mvals[2][64];
  __shared__ __align__(16) float l_lds[128];
  const int tid = threadIdx.x;
  const int w = tid >> 6, lane = tid & 63;
  const int g = lane >> 4, lr = lane & 15;
  const int l8 = lane >> 3, lch = lane & 7;
  const int gc = lch ^ l8;
  const int b = blockIdx.z, h = blockIdx.y, q0 = blockIdx.x * 128;
  const long base = (long)b * S_LEN * 1536;
  const int qcol = h * 64, kcol = 512 + h * 64;
  const u16* vhead = vt + (((long)b * 8 + h) * 64) * 2048;
  u16* q_t = kv;                                 // aliases k_t[0..1]; prologue only
  u16* vone = kv + 16384;
  const float SC = 0.18033688011112042f;         // 0.125 * log2(e)
  const int nv = nvalid[b];
  const int nt = (nv + 63) >> 6;

  auto stageKV = [&](int nb, int kb) {
    int kr = kb + w * 8 + l8;
    int cs = (kr < nv) ? cidx[b * 2048 + kr] : 0;
    __builtin_amdgcn_global_load_lds((gq_t*)(qkv + base + (long)cs * 1536 + kcol + gc * 8),
                                     (lq_t*)(kv + nb * 4096 + w * 512), 16, 0, 0);
    int row = w * 8 + l8;                        // d row; V already compacted along s
    __builtin_amdgcn_global_load_lds((gq_t*)(vhead + (long)row * 2048 + kb + gc * 8),
                                     (lq_t*)(kv + 8192 + nb * 4096 + w * 512), 16, 0, 0);
    if (tid < 64) mvals[nb][tid] = (kb + tid < nv) ? 0.f : -1e9f;
  };

  // ---- prologue: vone init + Q stage (aliased region) -> qf -> KV tile 0 ----
  {
    u32 val = ((tid >> 5) == 0) ? 0x3F803F80u : 0u;   // row 0 = bf16 ones, rows 1..15 zero
    *(u32*)((char*)vone + tid * 4) = val;
  }
#pragma unroll
  for (int i = 0; i < 2; ++i) {
    int e = i * 512 + tid;
    int row = e >> 3, ch = e & 7;
    uint4 v = *(const uint4*)(qkv + base + (long)(q0 + row) * 1536 + qcol + ch * 8);
    *(uint4*)((char*)q_t + row * 128 + ((ch ^ (row & 7)) << 4)) = v;
  }
  __syncthreads();
  short8 qf[2];
#pragma unroll
  for (int ks = 0; ks < 2; ++ks) {
    int row = w * 16 + lr;
    qf[ks] = *(const short8*)((const char*)q_t + row * 128 + (((ks * 4 + g) ^ (row & 7)) << 4));
  }
  __syncthreads();                               // all waves done with q_t
  stageKV(0, 0);
  __syncthreads();                               // tile 0 staged

  f32x4 o[5] = {};                               // o[4] = l accumulator (ones-row)

  for (int kt = 0; kt < nt; ++kt) {
    const int cur = kt & 1;
    if (kt + 1 < nt) stageKV(cur ^ 1, (kt + 1) * 64);

    // ---- S^T = K Q^T : s[ni][r] = S[key = ni*16+4g+r][q = lr] ----
    f32x4 s[4] = {};
    __builtin_amdgcn_s_setprio(1);
#pragma unroll
    for (int ks = 0; ks < 2; ++ks) {
#pragma unroll
      for (int ni = 0; ni < 4; ++ni) {
        int row = ni * 16 + lr;
        short8 kf = *(const short8*)((const char*)(kv + cur * 4096) + row * 128 + (((ks * 4 + g) ^ (row & 7)) << 4));
        s[ni] = __builtin_amdgcn_mfma_f32_16x16x32_bf16(kf, qf[ks], s[ni], 0, 0, 0);
      }
    }
    __builtin_amdgcn_s_setprio(0);
    // ---- max-free softmax numerator: P = exp2(s*SC + mask) ----
    float p[4][4];
#pragma unroll
    for (int ni = 0; ni < 4; ++ni) {
      const float4 mv = *(const float4*)&mvals[cur][ni * 16 + 4 * g];
      const float mva[4] = {mv.x, mv.y, mv.z, mv.w};
#pragma unroll
      for (int r = 0; r < 4; ++r)
        p[ni][r] = fexp2(fmaf(s[ni][r], SC, mva[r]));
    }
    u32 wv[4][2];
#pragma unroll
    for (int ni = 0; ni < 4; ++ni)
#pragma unroll
      for (int pp = 0; pp < 2; ++pp)
        asm("v_cvt_pk_bf16_f32 %0, %1, %2"
            : "=v"(wv[ni][pp]) : "v"(p[ni][2 * pp]), "v"(p[ni][2 * pp + 1]));

    // ---- in-register redistribution: lane needs P[q=lr][keys 32ks2+8g..+7] ----
    u32 x0 = wv[0][0], x1 = wv[0][1], y0 = wv[1][0], y1 = wv[1][1];
    swap32(x0, y0); swap32(x1, y1);
    swap16(x0, y0, lane); swap16(x1, y1, lane);
    short8 pa0 = mk8((u64)x0 | ((u64)x1 << 32), (u64)y0 | ((u64)y1 << 32));
    u32 x2 = wv[2][0], x3 = wv[2][1], y2 = wv[3][0], y3 = wv[3][1];
    swap32(x2, y2); swap32(x3, y3);
    swap16(x2, y2, lane); swap16(x3, y3, lane);
    short8 pa1 = mk8((u64)x2 | ((u64)x3 << 32), (u64)y2 | ((u64)y3 << 32));

    // ---- O += P V (nd=4 reads the shared ones-block -> l in o[4] at lr==0) ----
    __builtin_amdgcn_s_setprio(1);
#pragma unroll
    for (int ks2 = 0; ks2 < 2; ++ks2) {
      short8 pa = ks2 ? pa1 : pa0;
#pragma unroll
      for (int nd = 0; nd < 5; ++nd) {
        short8 vf;
        if (nd < 4) {
          int vrow = nd * 16 + lr;
          vf = *(const short8*)((const char*)(kv + 8192 + cur * 4096) + vrow * 128 + (((ks2 * 4 + g) ^ (vrow & 7)) << 4));
        } else {
          vf = *(const short8*)((const char*)vone + lr * 128 + (((ks2 * 4 + g) ^ (lr & 7)) << 4));
        }
        o[nd] = __builtin_amdgcn_mfma_f32_16x16x32_bf16(pa, vf, o[nd], 0, 0, 0);
      }
    }
    __builtin_amdgcn_s_setprio(0);
    if (kt + 1 < nt) __syncthreads();
  }
  // ---- epilogue: l lives in o[4][r] at lanes lr==0 ----
  if (lr == 0) {
#pragma unroll
    for (int r = 0; r < 4; ++r) l_lds[w * 16 + 4 * g + r] = o[4][r];
  }
  const float4 lv = *(const float4*)&l_lds[w * 16 + 4 * g];
  const float la[4] = {lv.x, lv.y, lv.z, lv.w};
  float inv[4];
#pragma unroll
  for (int r = 0; r < 4; ++r) inv[r] = 1.f / la[r];
#pragma unroll
  for (int nd = 0; nd < 4; ++nd)
#pragma unroll
    for (int r = 0; r < 4; ++r) {
      int tok = q0 + w * 16 + 4 * g + r;
      int col = h * 64 + nd * 16 + lr;
      ctx[((long)b * S_LEN + tok) * 512 + col] = f2bf(o[nd][r] * inv[r]);
    }
}

// ---------------- fused residual + layernorm, bf16 residual stream ----------------
template <bool FINAL>
__global__ __launch_bounds__(256) void ln_kernel(const u16* __restrict__ y,
                                                 const u16* __restrict__ res,
                                                 const float* __restrict__ gam,
                                                 const float* __restrict__ bet,
                                                 u16* __restrict__ xout,
                                                 float* __restrict__ outf) {
  const int row = blockIdx.x, t = threadIdx.x;
  const long o0 = (long)row * DM;
  const u32 yb = *(const u32*)(y + o0 + 2 * t);
  const u32 rb = *(const u32*)(res + o0 + 2 * t);
  float a0 = bf2f(yb << 16) + bf2f(rb << 16);
  float a1 = bf2f(yb & 0xFFFF0000u) + bf2f(rb & 0xFFFF0000u);
  float s1 = a0 + a1, s2 = a0 * a0 + a1 * a1;
#pragma unroll
  for (int m = 32; m >= 1; m >>= 1) {
    s1 += __shfl_xor(s1, m);
    s2 += __shfl_xor(s2, m);
  }
  __shared__ float w1[4], w2[4];
  if ((t & 63) == 0) { w1[t >> 6] = s1; w2[t >> 6] = s2; }
  __syncthreads();
  s1 = w1[0] + w1[1] + w1[2] + w1[3];
  s2 = w2[0] + w2[1] + w2[2] + w2[3];
  const float mu = s1 * (1.f / DM);
  const float rstd = rsqrtf(s2 * (1.f / DM) - mu * mu + 1e-5f);
  const float2 gv = *(const float2*)&gam[2 * t];
  const float2 bv = *(const float2*)&bet[2 * t];
  float r0 = (a0 - mu) * rstd * gv.x + bv.x;
  float r1 = (a1 - mu) * rstd * gv.y + bv.y;
  if constexpr (FINAL) {
    float2 ov; ov.x = r0; ov.y = r1;
    *(float2*)&outf[o0 + 2 * t] = ov;
  } else {
    u32 pk = (u32)f2bf(r0) | ((u32)f2bf(r1) << 16);
    *(u32*)&xout[o0 + 2 * t] = pk;
  }
}

extern "C" void kernel_launch(void* const* d_in, const int* in_sizes, int n_in,
                              void* d_out, int out_size, void* d_ws, size_t ws_size,
                              hipStream_t stream) {
  const int*   ids  = (const int*)d_in[0];
  const int*   amsk = (const int*)d_in[1];
  const float* te   = (const float*)d_in[2];
  const float* pe   = (const float*)d_in[3];
  const float* Wq   = (const float*)d_in[4];
  const float* Wk   = (const float*)d_in[5];
  const float* Wv   = (const float*)d_in[6];
  const float* Wo   = (const float*)d_in[7];
  const float* ln1g = (const float*)d_in[8];
  const float* ln1b = (const float*)d_in[9];
  const float* W1   = (const float*)d_in[10];
  const float* W2   = (const float*)d_in[11];
  const float* ln2g = (const float*)d_in[12];
  const float* ln2b = (const float*)d_in[13];
  float* out = (float*)d_out;

  // workspace layout; residual stream x is bf16
  char* p = (char*)d_ws;
  u16* x     = (u16*)p;   p += (long)NTOK * DM * 2;
  u16* qkv   = (u16*)p;   p += (long)NTOK * 1536 * 2;
  u16* ctx   = (u16*)p;   p += (long)NTOK * DM * 2;
  u16* tmp   = (u16*)p;   p += (long)NTOK * DM * 2;
  u16* hb    = (u16*)p;   p += (long)NTOK * 2048 * 2;
  u16* WqkvT = (u16*)p;   p += (long)4 * 1536 * 512 * 2;
  u16* WoT   = (u16*)p;   p += (long)4 * 512 * 512 * 2;
  u16* W1T   = (u16*)p;   p += (long)4 * 2048 * 512 * 2;
  u16* W2T   = (u16*)p;   p += (long)4 * 512 * 2048 * 2;
  int* cidx  = (int*)p;   p += (long)B_SZ * S_LEN * 4;
  int* cmap  = (int*)p;   p += (long)B_SZ * S_LEN * 4;
  int* nval  = (int*)p;   p += 64;
  if ((size_t)(p - (char*)d_ws) > ws_size) return;  // insufficient scratch
  // vt[b][h][d][cs] (8 MB) aliases hb: written by QKV GEMM, read by attn, dead before W1.
  u16* vt = hb;

  compact_kernel<<<B_SZ, 256, 0, stream>>>(amsk, cidx, cmap, nval);
  wconv_all<<<3072, 256, 0, stream>>>(Wq, Wk, Wv, Wo, W1, W2, WqkvT, WoT, W1T, W2T);
  embed_kernel<<<NTOK * 128 / 256, 256, 0, stream>>>(ids, te, pe, x);

  for (int l = 0; l < 4; ++l) {
    // fused QKV projection: [8192,512] @ [512,1536]; BM=256; V -> vt (compacted)
    gemm_kernel<256, 64, false, true, false><<<dim3(1536 / 64, NTOK / 256), 512, 0, stream>>>(
        x, WqkvT + (long)l * 1536 * 512, qkv, vt, cmap, NTOK, 1536, 512);
    attn_kernel<<<dim3(S_LEN / 128, 8, B_SZ), 512, 0, stream>>>(qkv, vt, cidx, nval, ctx);
    // Wo: SWAPC coalesced C^T epilogue
    gemm_kernel<128, 64, false, false, true><<<dim3(512 / 64, NTOK / 128), 256, 0, stream>>>(
        ctx, WoT + (long)l * 512 * 512, tmp, nullptr, nullptr, NTOK, 512, 512);
    ln_kernel<false><<<NTOK, 256, 0, stream>>>(tmp, x, ln1g + l * 512, ln1b + l * 512, x, nullptr);
    // W1: BM=256, ReLU, SWAPC
    gemm_kernel<256, 64, true, false, true><<<dim3(2048 / 64, NTOK / 256), 512, 0, stream>>>(
        x, W1T + (long)l * 2048 * 512, hb, nullptr, nullptr, NTOK, 2048, 512);
    gemm_kernel<128, 64, false, false, true><<<dim3(512 / 64, NTOK / 128), 256, 0, stream>>>(
        hb, W2T + (long)l * 512 * 2048, tmp, nullptr, nullptr, NTOK, 512, 2048);
    if (l == 3)
      ln_kernel<true><<<NTOK, 256, 0, stream>>>(tmp, x, ln2g + l * 512, ln2b + l * 512, nullptr, out);
    else
      ln_kernel<false><<<NTOK, 256, 0, stream>>>(tmp, x, ln2g + l * 512, ln2b + l * 512, x, nullptr);
  }
}